// Round 1
// baseline (261.849 us; speedup 1.0000x reference)
//
#include <hip/hip_runtime.h>

// ---------------------------------------------------------------------------
// Compile-time real-spherical-harmonic Clebsch-Gordan tables.
// Replicates the reference's _cg_complex / _u / _cg_real in C++17 constexpr,
// so all CG values fold to literal constants in the kernel and analytic
// zeros are eliminated at compile time.
// ---------------------------------------------------------------------------
namespace cgx {

struct Cplx { double re, im; };

constexpr Cplx cmul(Cplx a, Cplx b) {
  return Cplx{a.re * b.re - a.im * b.im, a.re * b.im + a.im * b.re};
}

constexpr double cfact(int n) {
  double r = 1.0;
  for (int i = 2; i <= n; i++) r *= (double)i;
  return r;
}

constexpr double cabs_(double x) { return x < 0.0 ? -x : x; }

constexpr double csqrt_(double x) {
  if (x <= 0.0) return 0.0;
  double g = x > 1.0 ? x : 1.0;
  for (int it = 0; it < 80; ++it) g = 0.5 * (g + x / g);
  return g;
}

// Complex-basis CG <l3 m3 | l1 m1 l2 m2>, Condon-Shortley.
// Max dims: l1,l2 <= 2 (5), l3 <= 4 (9).
struct CGC { double v[5][5][9]; };

constexpr CGC cg_complex(int l1, int l2, int l3) {
  CGC C{};
  for (int m1 = -l1; m1 <= l1; m1++) {
    for (int m2 = -l2; m2 <= l2; m2++) {
      int m3 = m1 + m2;
      if (m3 < -l3 || m3 > l3) continue;
      double pre = csqrt_((double)(2 * l3 + 1) * cfact(l1 + l2 - l3) *
                          cfact(l1 - l2 + l3) * cfact(-l1 + l2 + l3) /
                          cfact(l1 + l2 + l3 + 1));
      pre *= csqrt_(cfact(l3 + m3) * cfact(l3 - m3) * cfact(l1 - m1) *
                    cfact(l1 + m1) * cfact(l2 - m2) * cfact(l2 + m2));
      double s = 0.0;
      for (int k = 0; k <= l1 + l2 - l3; k++) {
        int d1 = l1 + l2 - l3 - k, d2 = l1 - m1 - k, d3 = l2 + m2 - k;
        int d4 = l3 - l2 + m1 + k, d5 = l3 - l1 - m2 + k;
        if (d1 < 0 || d2 < 0 || d3 < 0 || d4 < 0 || d5 < 0) continue;
        double d = cfact(k) * cfact(d1) * cfact(d2) * cfact(d3) * cfact(d4) * cfact(d5);
        s += ((k & 1) ? -1.0 : 1.0) / d;
      }
      C.v[m1 + l1][m2 + l2][m3 + l3] = pre * s;
    }
  }
  return C;
}

// Complex -> real SH change of basis, rows = real m index.
struct UMat { Cplx v[9][9]; };

constexpr UMat umat(int l) {
  UMat U{};
  double is2 = csqrt_(0.5);
  U.v[l][l] = Cplx{1.0, 0.0};
  for (int m = 1; m <= l; m++) {
    double sgn = (m & 1) ? -1.0 : 1.0;
    U.v[l + m][l + m] = Cplx{sgn * is2, 0.0};
    U.v[l + m][l - m] = Cplx{is2, 0.0};
    U.v[l - m][l - m] = Cplx{0.0, is2};
    U.v[l - m][l + m] = Cplx{0.0, -sgn * is2};
  }
  return U;
}

struct CGR { float v[5][5][9]; };

constexpr CGR cg_real(int l1, int l2, int l3) {
  CGC C = cg_complex(l1, l2, l3);
  UMat U1 = umat(l1), U2 = umat(l2), U3 = umat(l3);
  double re[5][5][9]{}, im[5][5][9]{};
  double maxre = 0.0, maxim = 0.0;
  for (int a = 0; a < 2 * l1 + 1; a++)
    for (int b = 0; b < 2 * l2 + 1; b++)
      for (int c = 0; c < 2 * l3 + 1; c++) {
        double ar = 0.0, ai = 0.0;
        for (int i = 0; i < 2 * l1 + 1; i++) {
          Cplx u1 = U1.v[a][i];
          if (u1.re == 0.0 && u1.im == 0.0) continue;
          for (int j = 0; j < 2 * l2 + 1; j++) {
            Cplx u2 = U2.v[b][j];
            if (u2.re == 0.0 && u2.im == 0.0) continue;
            // complex CG nonzero only at m3 = m1 + m2
            int k0 = (i - l1) + (j - l2) + l3;
            if (k0 < 0 || k0 > 2 * l3) continue;
            double cv = C.v[i][j][k0];
            if (cv == 0.0) continue;
            Cplx u3 = U3.v[c][k0];
            if (u3.re == 0.0 && u3.im == 0.0) continue;
            Cplx u12 = cmul(u1, u2);
            Cplx t = cmul(u12, Cplx{u3.re, -u3.im});
            ar += t.re * cv;
            ai += t.im * cv;
          }
        }
        re[a][b][c] = ar;
        im[a][b][c] = ai;
        if (cabs_(ar) > maxre) maxre = cabs_(ar);
        if (cabs_(ai) > maxim) maxim = cabs_(ai);
      }
  CGR R{};
  bool useim = maxim > maxre;
  for (int a = 0; a < 2 * l1 + 1; a++)
    for (int b = 0; b < 2 * l2 + 1; b++)
      for (int c = 0; c < 2 * l3 + 1; c++)
        R.v[a][b][c] = (float)(useim ? im[a][b][c] : re[a][b][c]);
  return R;
}

}  // namespace cgx

// ---------------------------------------------------------------------------
// Per-coupling contraction: out[k] += halfmix * sum_ij cg[i][j][k] xa[i] xb[j]
// CG values fold to literals; zero terms are branch-eliminated at -O3.
// ---------------------------------------------------------------------------
template <int L1, int L2, int LO>
__device__ __forceinline__ void do_coupling(const float* xa, const float* xb,
                                            float halfmix, float* out) {
  constexpr cgx::CGR t = cgx::cg_real(L1, L2, LO);
#pragma unroll
  for (int k = 0; k < 2 * LO + 1; k++) {
    float tp = 0.0f;
#pragma unroll
    for (int i = 0; i < 2 * L1 + 1; i++) {
#pragma unroll
      for (int j = 0; j < 2 * L2 + 1; j++) {
        const float cv = t.v[i][j][k];
        if (cv > 1e-7f || cv < -1e-7f)  // folds: constant condition
          tp = fmaf(cv * xa[i], xb[j], tp);
      }
    }
    out[k] = fmaf(halfmix, tp, out[k]);
  }
}

// Layout constants (match reference):
//  DIM_IN = 1152: x0 @ 0 (1x128), x1 @ 128 (3x128), x2 @ 512 (5x128)
//  DIM_OUT = 3200: o0 @ 0 (1x128), o1 @ 128 (3x128), o2 @ 512 (5x128),
//                  o3 @ 1152 (7x128), o4 @ 2048 (9x128)
//  keep_coeff: l=0 @ 0, l=1 @ 128, l=2 @ 256
//  mix_coeff: 19 couplings x 128 channels, lo-major enumeration order.

__global__ __launch_bounds__(256) void selfmix_kernel(
    const float* __restrict__ x, const float* __restrict__ keep,
    const float* __restrict__ mix, float* __restrict__ out, int B) {
  int tid = blockIdx.x * 256 + threadIdx.x;
  int b = tid >> 7;
  int c = tid & 127;
  if (b >= B) return;

  const float* xb = x + (size_t)b * 1152;
  float x0a[1];
  float x1[3], x2[5];
  x0a[0] = xb[c];
#pragma unroll
  for (int m = 0; m < 3; m++) x1[m] = xb[128 + m * 128 + c];
#pragma unroll
  for (int m = 0; m < 5; m++) x2[m] = xb[512 + m * 128 + c];

  float mx[19];
#pragma unroll
  for (int i = 0; i < 19; i++) mx[i] = 0.5f * mix[i * 128 + c];

  // accumulators initialized with the keep (skip) path
  float o0[1], o1[3], o2[5], o3[7], o4[9];
  o0[0] = keep[c] * x0a[0];
  float k1 = keep[128 + c];
#pragma unroll
  for (int m = 0; m < 3; m++) o1[m] = k1 * x1[m];
  float k2 = keep[256 + c];
#pragma unroll
  for (int m = 0; m < 5; m++) o2[m] = k2 * x2[m];
#pragma unroll
  for (int m = 0; m < 7; m++) o3[m] = 0.0f;
#pragma unroll
  for (int m = 0; m < 9; m++) o4[m] = 0.0f;

  // couplings in mix-offset order: (lo, l1, l2)
  do_coupling<0, 0, 0>(x0a, x0a, mx[0], o0);
  do_coupling<1, 1, 0>(x1, x1, mx[1], o0);
  do_coupling<2, 2, 0>(x2, x2, mx[2], o0);

  do_coupling<0, 1, 1>(x0a, x1, mx[3], o1);
  do_coupling<1, 0, 1>(x1, x0a, mx[4], o1);
  do_coupling<1, 1, 1>(x1, x1, mx[5], o1);
  do_coupling<1, 2, 1>(x1, x2, mx[6], o1);
  do_coupling<2, 1, 1>(x2, x1, mx[7], o1);
  do_coupling<2, 2, 1>(x2, x2, mx[8], o1);

  do_coupling<0, 2, 2>(x0a, x2, mx[9], o2);
  do_coupling<1, 1, 2>(x1, x1, mx[10], o2);
  do_coupling<1, 2, 2>(x1, x2, mx[11], o2);
  do_coupling<2, 0, 2>(x2, x0a, mx[12], o2);
  do_coupling<2, 1, 2>(x2, x1, mx[13], o2);
  do_coupling<2, 2, 2>(x2, x2, mx[14], o2);

  do_coupling<1, 2, 3>(x1, x2, mx[15], o3);
  do_coupling<2, 1, 3>(x2, x1, mx[16], o3);
  do_coupling<2, 2, 3>(x2, x2, mx[17], o3);

  do_coupling<2, 2, 4>(x2, x2, mx[18], o4);

  float* ob = out + (size_t)b * 3200;
  ob[c] = o0[0];
#pragma unroll
  for (int m = 0; m < 3; m++) ob[128 + m * 128 + c] = o1[m];
#pragma unroll
  for (int m = 0; m < 5; m++) ob[512 + m * 128 + c] = o2[m];
#pragma unroll
  for (int m = 0; m < 7; m++) ob[1152 + m * 128 + c] = o3[m];
#pragma unroll
  for (int m = 0; m < 9; m++) ob[2048 + m * 128 + c] = o4[m];
}

extern "C" void kernel_launch(void* const* d_in, const int* in_sizes, int n_in,
                              void* d_out, int out_size, void* d_ws, size_t ws_size,
                              hipStream_t stream) {
  const float* x = (const float*)d_in[0];
  const float* keep = (const float*)d_in[1];
  const float* mix = (const float*)d_in[2];
  float* out = (float*)d_out;
  int B = in_sizes[0] / 1152;  // 16384
  int total = B * 128;
  int blocks = (total + 255) / 256;
  selfmix_kernel<<<blocks, 256, 0, stream>>>(x, keep, mix, out, B);
}